// Round 13
// baseline (149.999 us; speedup 1.0000x reference)
//
#include <hip/hip_runtime.h>
#include <hip/hip_bf16.h>
#include <math.h>

#define PI_F 3.14159265358979323846f

// ---------------------------------------------------------------------------
// Kernel 1: build the fixed 64x64 complex unitary U. One block per INPUT
// basis state b. Layout: Umat[(j*64 + k)*2 + {0,1}] = {Re,Im} of U[k][j];
// the chunk slice [16c,16c+16) of row j is one aligned 64-byte line.
// ---------------------------------------------------------------------------
__global__ __launch_bounds__(64) void build_u(const float* __restrict__ qw,
                                              float* __restrict__ Umat) {
    const int l = threadIdx.x;   // amplitude index k (0..63)
    const int b = blockIdx.x;    // input basis state j (0..63)

    float ar = (l == b) ? 1.0f : 0.0f;
    float ai = 0.0f;

    #pragma unroll
    for (int i = 0; i < 6; ++i) {
        const int mask = 1 << (5 - i);
        float th = 0.5f * qw[0 * 6 + i];
        float c = cosf(th), sn = sinf(th);
        float pr = __shfl_xor(ar, mask);
        float pi = __shfl_xor(ai, mask);
        float nr = c * ar + sn * pi;
        float ni = c * ai - sn * pr;
        ar = nr; ai = ni;
        th = 0.5f * qw[1 * 6 + i];
        c = cosf(th); sn = sinf(th);
        float zn = (l & mask) ? 1.0f : -1.0f;
        nr = c * ar - zn * sn * ai;
        ni = c * ai + zn * sn * ar;
        ar = nr; ai = ni;
    }

    #pragma unroll
    for (int i = 0; i < 6; ++i) {
        const int ctrl = i, tgt = (i + 1) % 6;
        const int cm = 1 << (5 - ctrl), tm = 1 << (5 - tgt);
        float pr = __shfl_xor(ar, tm);
        float pi = __shfl_xor(ai, tm);
        bool take = (l & cm) != 0;
        ar = take ? pr : ar;
        ai = take ? pi : ai;
    }

    #pragma unroll
    for (int i = 0; i < 6; ++i) {
        const int mask = 1 << (5 - i);
        float th = 0.5f * qw[2 * 6 + i];
        float c = cosf(th), sn = sinf(th);
        float pr = __shfl_xor(ar, mask);
        float pi = __shfl_xor(ai, mask);
        float sg = (l & mask) ? sn : -sn;
        float nr = c * ar + sg * pr;
        float ni = c * ai + sg * pi;
        ar = nr; ai = ni;
        th = 0.5f * qw[3 * 6 + i];
        c = cosf(th); sn = sinf(th);
        float zn = (l & mask) ? 1.0f : -1.0f;
        nr = c * ar - zn * sn * ai;
        ni = c * ai + zn * sn * ar;
        ar = nr; ai = ni;
    }

    #pragma unroll
    for (int i = 0; i < 6; i += 2) {
        const int cm = 1 << (5 - i), tm = 1 << (5 - (i + 1));
        float pr = __shfl_xor(ar, tm);
        float pi = __shfl_xor(ai, tm);
        bool take = (l & cm) != 0;
        ar = take ? pr : ar;
        ai = take ? pi : ai;
    }

    #pragma unroll
    for (int i = 0; i < 6; ++i) {
        const int mask = 1 << (5 - i);
        float th = 0.5f * qw[4 * 6 + i];
        float c = cosf(th), sn = sinf(th);
        float pr = __shfl_xor(ar, mask);
        float pi = __shfl_xor(ai, mask);
        float nr = c * ar + sn * pi;
        float ni = c * ai - sn * pr;
        ar = nr; ai = ni;
    }

    Umat[(b * 64 + l) * 2 + 0] = ar;
    Umat[(b * 64 + l) * 2 + 1] = ai;
}

// ---------------------------------------------------------------------------
// Front MLP with a 2-stage, 8xfloat4-per-stage software-pipelined Layer 1:
// 16 x-loads in flight per thread (the grid caps TLP at 4 waves/SIMD, so
// registers are free up to 128 -- spend them on memory-level parallelism).
// ---------------------------------------------------------------------------
__device__ __forceinline__ void front_mlp(
    const float* __restrict__ x, int s_ld,
    const float* __restrict__ W1, const float* __restrict__ b1,
    const float* __restrict__ W2, const float* __restrict__ b2,
    const float* __restrict__ W3, const float* __restrict__ b3,
    float lo[8], float hi[8])
{
    float h1[32];
    #pragma unroll
    for (int o = 0; o < 32; ++o) h1[o] = b1[o];
    const float4* x4 = reinterpret_cast<const float4*>(x + (size_t)s_ld * 128);

    float4 XA0, XA1, XA2, XA3, XA4, XA5, XA6, XA7;
    float4 XB0, XB1, XB2, XB3, XB4, XB5, XB6, XB7;

    // one float4 worth of FMAs against W1 rows [base, base+4)
    #define L1_F4(XV, base)                                                   \
        {                                                                     \
            const float* w = W1 + (base) * 32;                                \
            _Pragma("unroll")                                                 \
            for (int o = 0; o < 32; ++o) h1[o] = fmaf(XV.x, w[o], h1[o]);     \
            _Pragma("unroll")                                                 \
            for (int o = 0; o < 32; ++o) h1[o] = fmaf(XV.y, w[32 + o], h1[o]);\
            _Pragma("unroll")                                                 \
            for (int o = 0; o < 32; ++o) h1[o] = fmaf(XV.z, w[64 + o], h1[o]);\
            _Pragma("unroll")                                                 \
            for (int o = 0; o < 32; ++o) h1[o] = fmaf(XV.w, w[96 + o], h1[o]);\
        }

    // load 8 float4 (32 floats = quarter row) into named stage registers
    #define L1_LOAD(P, c)                                                     \
        {                                                                     \
            P##0 = x4[(c) * 8 + 0]; P##1 = x4[(c) * 8 + 1];                   \
            P##2 = x4[(c) * 8 + 2]; P##3 = x4[(c) * 8 + 3];                   \
            P##4 = x4[(c) * 8 + 4]; P##5 = x4[(c) * 8 + 5];                   \
            P##6 = x4[(c) * 8 + 6]; P##7 = x4[(c) * 8 + 7];                   \
        }

    // consume one stage (32 floats starting at column (c)*32)
    #define L1_FMA(P, c)                                                      \
        L1_F4(P##0, (c) * 32 + 0)  L1_F4(P##1, (c) * 32 + 4)                  \
        L1_F4(P##2, (c) * 32 + 8)  L1_F4(P##3, (c) * 32 + 12)                 \
        L1_F4(P##4, (c) * 32 + 16) L1_F4(P##5, (c) * 32 + 20)                 \
        L1_F4(P##6, (c) * 32 + 24) L1_F4(P##7, (c) * 32 + 28)

    L1_LOAD(XA, 0)
    L1_LOAD(XB, 1)
    L1_FMA(XA, 0)
    L1_LOAD(XA, 2)
    L1_FMA(XB, 1)
    L1_LOAD(XB, 3)
    L1_FMA(XA, 2)
    L1_FMA(XB, 3)

    #undef L1_F4
    #undef L1_LOAD
    #undef L1_FMA

    #pragma unroll
    for (int o = 0; o < 32; ++o) h1[o] = fmaxf(h1[o], 0.0f);

    // Layer 2: 32 -> 16
    float h2[16];
    #pragma unroll
    for (int o = 0; o < 16; ++o) h2[o] = b2[o];
    #pragma unroll
    for (int j = 0; j < 32; ++j) {
        #pragma unroll
        for (int o = 0; o < 16; ++o) h2[o] = fmaf(h1[j], W2[j * 16 + o], h2[o]);
    }
    #pragma unroll
    for (int o = 0; o < 16; ++o) h2[o] = fmaxf(h2[o], 0.0f);

    // Layer 3: angles -> half-angle cos/sin
    float cq[6], sq[6];
    #pragma unroll
    for (int q = 0; q < 6; ++q) {
        float t = b3[q];
        #pragma unroll
        for (int j = 0; j < 16; ++j) t = fmaf(h2[j], W3[j * 6 + q], t);
        t = tanhf(t);
        t = fminf(1.0f, fmaxf(-1.0f, t));
        float half = t * (0.5f * PI_F);
        sq[q] = sinf(half);
        cq[q] = cosf(half);
    }

    // half-product tables: psi[j] = hi[j>>3] * lo[j&7]
    {
        float f3[2] = {cq[3], sq[3]};
        float f4[2] = {cq[4], sq[4]};
        float f5[2] = {cq[5], sq[5]};
        #pragma unroll
        for (int m = 0; m < 8; ++m)
            lo[m] = f3[(m >> 2) & 1] * f4[(m >> 1) & 1] * f5[m & 1];
        float f0[2] = {cq[0], sq[0]};
        float f1[2] = {cq[1], sq[1]};
        float f2[2] = {cq[2], sq[2]};
        #pragma unroll
        for (int m = 0; m < 8; ++m)
            hi[m] = f0[(m >> 2) & 1] * f1[(m >> 1) & 1] * f2[m & 1];
    }
}

__device__ __forceinline__ void gemv_and_back(
    const float lo[8], const float hi[8],
    const float* __restrict__ Umat,
    const float* __restrict__ W4, const float* __restrict__ b4,
    const float* __restrict__ W5, const float* __restrict__ b5,
    float* __restrict__ out, int s, int B)
{
    float acc0 = 0.f, acc1 = 0.f, acc2 = 0.f, acc3 = 0.f, acc4 = 0.f, acc5 = 0.f;

    #pragma unroll 1
    for (int c = 0; c < 8; ++c) {
        const float* ub = Umat + c * 16;      // uniform base for this chunk
        float re[8], im[8];
        #pragma unroll
        for (int kk = 0; kk < 8; ++kk) { re[kk] = 0.0f; im[kk] = 0.0f; }

        #pragma unroll
        for (int jh = 0; jh < 8; ++jh) {
            #pragma unroll
            for (int jl = 0; jl < 8; ++jl) {
                float v = hi[jh] * lo[jl];
                const float* u = ub + (jh * 8 + jl) * 128;  // uniform -> broadcast
                #pragma unroll
                for (int kk = 0; kk < 8; ++kk) {
                    re[kk] = fmaf(u[2 * kk],     v, re[kk]);
                    im[kk] = fmaf(u[2 * kk + 1], v, im[kk]);
                }
            }
        }

        float s0 = (c & 4) ? -1.0f : 1.0f;
        float s1 = (c & 2) ? -1.0f : 1.0f;
        float s2 = (c & 1) ? -1.0f : 1.0f;
        #pragma unroll
        for (int kk = 0; kk < 8; ++kk) {
            float p = re[kk] * re[kk] + im[kk] * im[kk];
            acc0 = fmaf(s0, p, acc0);
            acc1 = fmaf(s1, p, acc1);
            acc2 = fmaf(s2, p, acc2);
            acc3 += (kk & 4) ? -p : p;
            acc4 += (kk & 2) ? -p : p;
            acc5 += (kk & 1) ? -p : p;
        }
    }

    float qv[6] = {acc0, acc1, acc2, acc3, acc4, acc5};

    float h4[16];
    #pragma unroll
    for (int o = 0; o < 16; ++o) h4[o] = b4[o];
    #pragma unroll
    for (int q = 0; q < 6; ++q) {
        #pragma unroll
        for (int o = 0; o < 16; ++o) h4[o] = fmaf(qv[q], W4[q * 16 + o], h4[o]);
    }
    #pragma unroll
    for (int o = 0; o < 16; ++o) h4[o] = fmaxf(h4[o], 0.0f);

    float o5[20];
    #pragma unroll
    for (int o = 0; o < 20; ++o) {
        float t = b5[o];
        #pragma unroll
        for (int j = 0; j < 16; ++j) t = fmaf(h4[j], W5[j * 20 + o], t);
        o5[o] = t;
    }

    if (s < B) {
        float4* outv = reinterpret_cast<float4*>(out + (size_t)s * 20);
        #pragma unroll
        for (int i = 0; i < 5; ++i)
            outv[i] = make_float4(o5[4 * i], o5[4 * i + 1], o5[4 * i + 2], o5[4 * i + 3]);
    }
}

// ---------------------------------------------------------------------------
// Split kernel A: front MLP -> 16 table floats per sample (SoA planes).
// amdgpu_waves_per_eu(4): the grid caps occupancy at 4 waves/SIMD anyway, so
// tell the allocator 4 is enough (128-VGPR budget) and let the pipelined
// loads stay hoisted instead of being compressed back to VGPR=32.
// ---------------------------------------------------------------------------
__global__ __launch_bounds__(256)
__attribute__((amdgpu_waves_per_eu(4)))
void front_kernel(
    const float* __restrict__ x,
    const float* __restrict__ W1, const float* __restrict__ b1,
    const float* __restrict__ W2, const float* __restrict__ b2,
    const float* __restrict__ W3, const float* __restrict__ b3,
    float* __restrict__ tab, int B)
{
    const int s = blockIdx.x * 256 + threadIdx.x;
    const int s_ld = (s < B) ? s : (B - 1);

    float lo[8], hi[8];
    front_mlp(x, s_ld, W1, b1, W2, b2, W3, b3, lo, hi);

    if (s < B) {
        #pragma unroll
        for (int i = 0; i < 8; ++i) tab[(size_t)i * B + s] = lo[i];
        #pragma unroll
        for (int i = 0; i < 8; ++i) tab[(size_t)(8 + i) * B + s] = hi[i];
    }
}

// ---------------------------------------------------------------------------
// Split kernel B: GEMV + back MLP (unchanged from R12 -- the good half).
// ---------------------------------------------------------------------------
__global__ __launch_bounds__(256) void gemv_kernel(
    const float* __restrict__ tab,
    const float* __restrict__ Umat,
    const float* __restrict__ W4, const float* __restrict__ b4,
    const float* __restrict__ W5, const float* __restrict__ b5,
    float* __restrict__ out, int B)
{
    const int s = blockIdx.x * 256 + threadIdx.x;
    const int s_ld = (s < B) ? s : (B - 1);

    float lo[8], hi[8];
    #pragma unroll
    for (int i = 0; i < 8; ++i) lo[i] = tab[(size_t)i * B + s_ld];
    #pragma unroll
    for (int i = 0; i < 8; ++i) hi[i] = tab[(size_t)(8 + i) * B + s_ld];

    gemv_and_back(lo, hi, Umat, W4, b4, W5, b5, out, s, B);
}

// ---------------------------------------------------------------------------
// Fallback single kernel (used only if ws_size is too small for the planes).
// ---------------------------------------------------------------------------
__global__ __launch_bounds__(256) void fused_single(
    const float* __restrict__ x,
    const float* __restrict__ W1, const float* __restrict__ b1,
    const float* __restrict__ W2, const float* __restrict__ b2,
    const float* __restrict__ W3, const float* __restrict__ b3,
    const float* __restrict__ W4, const float* __restrict__ b4,
    const float* __restrict__ W5, const float* __restrict__ b5,
    const float* __restrict__ Umat,
    float* __restrict__ out, int B)
{
    const int s = blockIdx.x * 256 + threadIdx.x;
    const int s_ld = (s < B) ? s : (B - 1);

    float lo[8], hi[8];
    front_mlp(x, s_ld, W1, b1, W2, b2, W3, b3, lo, hi);
    gemv_and_back(lo, hi, Umat, W4, b4, W5, b5, out, s, B);
}

// ---------------------------------------------------------------------------
extern "C" void kernel_launch(void* const* d_in, const int* in_sizes, int n_in,
                              void* d_out, int out_size, void* d_ws, size_t ws_size,
                              hipStream_t stream) {
    const float* x  = (const float*)d_in[0];
    const float* W1 = (const float*)d_in[1];
    const float* b1 = (const float*)d_in[2];
    const float* W2 = (const float*)d_in[3];
    const float* b2 = (const float*)d_in[4];
    const float* W3 = (const float*)d_in[5];
    const float* b3 = (const float*)d_in[6];
    const float* qw = (const float*)d_in[7];
    const float* W4 = (const float*)d_in[8];
    const float* b4 = (const float*)d_in[9];
    const float* W5 = (const float*)d_in[10];
    const float* b5 = (const float*)d_in[11];
    float* out = (float*)d_out;

    const int B = in_sizes[0] / 128;
    const int nblk = (B + 255) / 256;

    float* Umat = (float*)d_ws;                       // 32 KB
    float* tab  = (float*)d_ws + 8192;                // 16 * B floats
    const size_t need = 8192u * 4 + (size_t)16 * 4 * (size_t)B;

    build_u<<<64, 64, 0, stream>>>(qw, Umat);

    if (ws_size >= need) {
        front_kernel<<<nblk, 256, 0, stream>>>(x, W1, b1, W2, b2, W3, b3, tab, B);
        gemv_kernel<<<nblk, 256, 0, stream>>>(tab, Umat, W4, b4, W5, b5, out, B);
    } else {
        fused_single<<<nblk, 256, 0, stream>>>(
            x, W1, b1, W2, b2, W3, b3, W4, b4, W5, b5, Umat, out, B);
    }
}

// Round 14
// 137.380 us; speedup vs baseline: 1.0919x; 1.0919x over previous
//
#include <hip/hip_runtime.h>
#include <hip/hip_bf16.h>
#include <math.h>

#define PI_F 3.14159265358979323846f

// ---------------------------------------------------------------------------
// Kernel 1: build the fixed 64x64 complex unitary U. One block per INPUT
// basis state b. Layout: Umat[(j*64 + k)*2 + {0,1}] = {Re,Im} of U[k][j].
// ---------------------------------------------------------------------------
__global__ __launch_bounds__(64) void build_u(const float* __restrict__ qw,
                                              float* __restrict__ Umat) {
    const int l = threadIdx.x;   // amplitude index k (0..63)
    const int b = blockIdx.x;    // input basis state j (0..63)

    float ar = (l == b) ? 1.0f : 0.0f;
    float ai = 0.0f;

    #pragma unroll
    for (int i = 0; i < 6; ++i) {
        const int mask = 1 << (5 - i);
        float th = 0.5f * qw[0 * 6 + i];
        float c = cosf(th), sn = sinf(th);
        float pr = __shfl_xor(ar, mask);
        float pi = __shfl_xor(ai, mask);
        float nr = c * ar + sn * pi;
        float ni = c * ai - sn * pr;
        ar = nr; ai = ni;
        th = 0.5f * qw[1 * 6 + i];
        c = cosf(th); sn = sinf(th);
        float zn = (l & mask) ? 1.0f : -1.0f;
        nr = c * ar - zn * sn * ai;
        ni = c * ai + zn * sn * ar;
        ar = nr; ai = ni;
    }

    #pragma unroll
    for (int i = 0; i < 6; ++i) {
        const int ctrl = i, tgt = (i + 1) % 6;
        const int cm = 1 << (5 - ctrl), tm = 1 << (5 - tgt);
        float pr = __shfl_xor(ar, tm);
        float pi = __shfl_xor(ai, tm);
        bool take = (l & cm) != 0;
        ar = take ? pr : ar;
        ai = take ? pi : ai;
    }

    #pragma unroll
    for (int i = 0; i < 6; ++i) {
        const int mask = 1 << (5 - i);
        float th = 0.5f * qw[2 * 6 + i];
        float c = cosf(th), sn = sinf(th);
        float pr = __shfl_xor(ar, mask);
        float pi = __shfl_xor(ai, mask);
        float sg = (l & mask) ? sn : -sn;
        float nr = c * ar + sg * pr;
        float ni = c * ai + sg * pi;
        ar = nr; ai = ni;
        th = 0.5f * qw[3 * 6 + i];
        c = cosf(th); sn = sinf(th);
        float zn = (l & mask) ? 1.0f : -1.0f;
        nr = c * ar - zn * sn * ai;
        ni = c * ai + zn * sn * ar;
        ar = nr; ai = ni;
    }

    #pragma unroll
    for (int i = 0; i < 6; i += 2) {
        const int cm = 1 << (5 - i), tm = 1 << (5 - (i + 1));
        float pr = __shfl_xor(ar, tm);
        float pi = __shfl_xor(ai, tm);
        bool take = (l & cm) != 0;
        ar = take ? pr : ar;
        ai = take ? pi : ai;
    }

    #pragma unroll
    for (int i = 0; i < 6; ++i) {
        const int mask = 1 << (5 - i);
        float th = 0.5f * qw[4 * 6 + i];
        float c = cosf(th), sn = sinf(th);
        float pr = __shfl_xor(ar, mask);
        float pi = __shfl_xor(ai, mask);
        float nr = c * ar + sn * pi;
        float ni = c * ai - sn * pr;
        ar = nr; ai = ni;
    }

    Umat[(b * 64 + l) * 2 + 0] = ar;
    Umat[(b * 64 + l) * 2 + 1] = ai;
}

// ---------------------------------------------------------------------------
// Shared tail of the front MLP (layers 2,3 + tables). Verified since R3.
// ---------------------------------------------------------------------------
__device__ __forceinline__ void front_tail(
    const float h1[32],
    const float* __restrict__ W2, const float* __restrict__ b2,
    const float* __restrict__ W3, const float* __restrict__ b3,
    float lo[8], float hi[8])
{
    float h2[16];
    #pragma unroll
    for (int o = 0; o < 16; ++o) h2[o] = b2[o];
    #pragma unroll
    for (int j = 0; j < 32; ++j) {
        #pragma unroll
        for (int o = 0; o < 16; ++o) h2[o] = fmaf(h1[j], W2[j * 16 + o], h2[o]);
    }
    #pragma unroll
    for (int o = 0; o < 16; ++o) h2[o] = fmaxf(h2[o], 0.0f);

    float cq[6], sq[6];
    #pragma unroll
    for (int q = 0; q < 6; ++q) {
        float t = b3[q];
        #pragma unroll
        for (int j = 0; j < 16; ++j) t = fmaf(h2[j], W3[j * 6 + q], t);
        t = tanhf(t);
        t = fminf(1.0f, fmaxf(-1.0f, t));
        float half = t * (0.5f * PI_F);
        sq[q] = sinf(half);
        cq[q] = cosf(half);
    }

    {
        float f3[2] = {cq[3], sq[3]};
        float f4[2] = {cq[4], sq[4]};
        float f5[2] = {cq[5], sq[5]};
        #pragma unroll
        for (int m = 0; m < 8; ++m)
            lo[m] = f3[(m >> 2) & 1] * f4[(m >> 1) & 1] * f5[m & 1];
        float f0[2] = {cq[0], sq[0]};
        float f1[2] = {cq[1], sq[1]};
        float f2[2] = {cq[2], sq[2]};
        #pragma unroll
        for (int m = 0; m < 8; ++m)
            hi[m] = f0[(m >> 2) & 1] * f1[(m >> 1) & 1] * f2[m & 1];
    }
}

// ---------------------------------------------------------------------------
// Split kernel A: front MLP with COALESCED LDS-staged x.
// Layer-1 is K-tiled (4 tiles of 32 columns). Per tile: the block stages a
// 256-sample x 32-col slice (32 KB) with consecutive lanes reading
// consecutive float4 (1 KB/instruction, all lines fully used), then each
// thread ds_read_b128's its own row. LDS row stride = 36 floats: lanes 0..7
// hit banks 4l..4l+3 -> all 32 banks exactly once -> conflict-free b128.
// This removes the 64-transactions-per-load pattern that kept R12/R13
// latency-bound at VALUBusy ~35%.
// ---------------------------------------------------------------------------
__global__ __launch_bounds__(256) void front_kernel(
    const float* __restrict__ x,
    const float* __restrict__ W1, const float* __restrict__ b1,
    const float* __restrict__ W2, const float* __restrict__ b2,
    const float* __restrict__ W3, const float* __restrict__ b3,
    float* __restrict__ tab, int B)
{
    __shared__ float Ls[256 * 36];           // 36 KB

    const int tid = threadIdx.x;
    const long sbase = (long)blockIdx.x * 256;
    const int s = (int)(sbase + tid);

    const float4* xg = reinterpret_cast<const float4*>(x);  // x[s][c4] at s*32+c4

    float h1[32];
    #pragma unroll
    for (int o = 0; o < 32; ++o) h1[o] = b1[o];

    #pragma unroll 1
    for (int tile = 0; tile < 4; ++tile) {
        // ---- coalesced stage: 2048 float4 = 8 per thread
        #pragma unroll
        for (int i = 0; i < 8; ++i) {
            const int flat = i * 256 + tid;
            const int row = flat >> 3;        // 0..255
            const int c4  = flat & 7;         // 0..7
            long srow = sbase + row;
            if (srow >= B) srow = B - 1;
            float4 v = xg[(size_t)srow * 32 + tile * 8 + c4];
            *reinterpret_cast<float4*>(&Ls[row * 36 + c4 * 4]) = v;
        }
        __syncthreads();

        // ---- consume own row from LDS (conflict-free b128 reads)
        #pragma unroll
        for (int c4 = 0; c4 < 8; ++c4) {
            float4 xv = *reinterpret_cast<const float4*>(&Ls[tid * 36 + c4 * 4]);
            const float* w = W1 + (tile * 32 + c4 * 4) * 32;
            #pragma unroll
            for (int o = 0; o < 32; ++o) h1[o] = fmaf(xv.x, w[o], h1[o]);
            #pragma unroll
            for (int o = 0; o < 32; ++o) h1[o] = fmaf(xv.y, w[32 + o], h1[o]);
            #pragma unroll
            for (int o = 0; o < 32; ++o) h1[o] = fmaf(xv.z, w[64 + o], h1[o]);
            #pragma unroll
            for (int o = 0; o < 32; ++o) h1[o] = fmaf(xv.w, w[96 + o], h1[o]);
        }
        __syncthreads();                      // safe to overwrite next tile
    }

    #pragma unroll
    for (int o = 0; o < 32; ++o) h1[o] = fmaxf(h1[o], 0.0f);

    float lo[8], hi[8];
    front_tail(h1, W2, b2, W3, b3, lo, hi);

    if (s < B) {
        #pragma unroll
        for (int i = 0; i < 8; ++i) tab[(size_t)i * B + s] = lo[i];
        #pragma unroll
        for (int i = 0; i < 8; ++i) tab[(size_t)(8 + i) * B + s] = hi[i];
    }
}

// ---------------------------------------------------------------------------
// GEMV + back MLP (unchanged from R12 -- the working half).
// ---------------------------------------------------------------------------
__device__ __forceinline__ void gemv_and_back(
    const float lo[8], const float hi[8],
    const float* __restrict__ Umat,
    const float* __restrict__ W4, const float* __restrict__ b4,
    const float* __restrict__ W5, const float* __restrict__ b5,
    float* __restrict__ out, int s, int B)
{
    float acc0 = 0.f, acc1 = 0.f, acc2 = 0.f, acc3 = 0.f, acc4 = 0.f, acc5 = 0.f;

    #pragma unroll 1
    for (int c = 0; c < 8; ++c) {
        const float* ub = Umat + c * 16;      // uniform base for this chunk
        float re[8], im[8];
        #pragma unroll
        for (int kk = 0; kk < 8; ++kk) { re[kk] = 0.0f; im[kk] = 0.0f; }

        #pragma unroll
        for (int jh = 0; jh < 8; ++jh) {
            #pragma unroll
            for (int jl = 0; jl < 8; ++jl) {
                float v = hi[jh] * lo[jl];
                const float* u = ub + (jh * 8 + jl) * 128;  // uniform -> broadcast
                #pragma unroll
                for (int kk = 0; kk < 8; ++kk) {
                    re[kk] = fmaf(u[2 * kk],     v, re[kk]);
                    im[kk] = fmaf(u[2 * kk + 1], v, im[kk]);
                }
            }
        }

        float s0 = (c & 4) ? -1.0f : 1.0f;
        float s1 = (c & 2) ? -1.0f : 1.0f;
        float s2 = (c & 1) ? -1.0f : 1.0f;
        #pragma unroll
        for (int kk = 0; kk < 8; ++kk) {
            float p = re[kk] * re[kk] + im[kk] * im[kk];
            acc0 = fmaf(s0, p, acc0);
            acc1 = fmaf(s1, p, acc1);
            acc2 = fmaf(s2, p, acc2);
            acc3 += (kk & 4) ? -p : p;
            acc4 += (kk & 2) ? -p : p;
            acc5 += (kk & 1) ? -p : p;
        }
    }

    float qv[6] = {acc0, acc1, acc2, acc3, acc4, acc5};

    float h4[16];
    #pragma unroll
    for (int o = 0; o < 16; ++o) h4[o] = b4[o];
    #pragma unroll
    for (int q = 0; q < 6; ++q) {
        #pragma unroll
        for (int o = 0; o < 16; ++o) h4[o] = fmaf(qv[q], W4[q * 16 + o], h4[o]);
    }
    #pragma unroll
    for (int o = 0; o < 16; ++o) h4[o] = fmaxf(h4[o], 0.0f);

    float o5[20];
    #pragma unroll
    for (int o = 0; o < 20; ++o) {
        float t = b5[o];
        #pragma unroll
        for (int j = 0; j < 16; ++j) t = fmaf(h4[j], W5[j * 20 + o], t);
        o5[o] = t;
    }

    if (s < B) {
        float4* outv = reinterpret_cast<float4*>(out + (size_t)s * 20);
        #pragma unroll
        for (int i = 0; i < 5; ++i)
            outv[i] = make_float4(o5[4 * i], o5[4 * i + 1], o5[4 * i + 2], o5[4 * i + 3]);
    }
}

__global__ __launch_bounds__(256) void gemv_kernel(
    const float* __restrict__ tab,
    const float* __restrict__ Umat,
    const float* __restrict__ W4, const float* __restrict__ b4,
    const float* __restrict__ W5, const float* __restrict__ b5,
    float* __restrict__ out, int B)
{
    const int s = blockIdx.x * 256 + threadIdx.x;
    const int s_ld = (s < B) ? s : (B - 1);

    float lo[8], hi[8];
    #pragma unroll
    for (int i = 0; i < 8; ++i) lo[i] = tab[(size_t)i * B + s_ld];
    #pragma unroll
    for (int i = 0; i < 8; ++i) hi[i] = tab[(size_t)(8 + i) * B + s_ld];

    gemv_and_back(lo, hi, Umat, W4, b4, W5, b5, out, s, B);
}

// ---------------------------------------------------------------------------
extern "C" void kernel_launch(void* const* d_in, const int* in_sizes, int n_in,
                              void* d_out, int out_size, void* d_ws, size_t ws_size,
                              hipStream_t stream) {
    const float* x  = (const float*)d_in[0];
    const float* W1 = (const float*)d_in[1];
    const float* b1 = (const float*)d_in[2];
    const float* W2 = (const float*)d_in[3];
    const float* b2 = (const float*)d_in[4];
    const float* W3 = (const float*)d_in[5];
    const float* b3 = (const float*)d_in[6];
    const float* qw = (const float*)d_in[7];
    const float* W4 = (const float*)d_in[8];
    const float* b4 = (const float*)d_in[9];
    const float* W5 = (const float*)d_in[10];
    const float* b5 = (const float*)d_in[11];
    float* out = (float*)d_out;

    const int B = in_sizes[0] / 128;
    const int nblk = (B + 255) / 256;

    float* Umat = (float*)d_ws;                       // 32 KB
    float* tab  = (float*)d_ws + 8192;                // 16 * B floats

    build_u<<<64, 64, 0, stream>>>(qw, Umat);
    front_kernel<<<nblk, 256, 0, stream>>>(x, W1, b1, W2, b2, W3, b3, tab, B);
    gemv_kernel<<<nblk, 256, 0, stream>>>(tab, Umat, W4, b4, W5, b5, out, B);
}